// Round 3
// baseline (516.433 us; speedup 1.0000x reference)
//
#include <hip/hip_runtime.h>
#include <hip/hip_fp16.h>
#include <math.h>

#define NHEADS 12
#define SEQ 4096
#define BATCH 8

typedef _Float16 half8 __attribute__((ext_vector_type(8)));
typedef float floatx4 __attribute__((ext_vector_type(4)));

// ---------------- zero small accumulators ----------------
__global__ void zero_kernel(float* p, int n) {
  int i = blockIdx.x * 256 + threadIdx.x;
  if (i < n) p[i] = 0.f;
}

// ---------------- fp32 -> fp16 cast, 4 elems/thread ----------------
__global__ void cast_f2h(const float* __restrict__ in, __half* __restrict__ out, int n) {
  int i = (blockIdx.x * 256 + threadIdx.x) * 4;
  if (i < n) {
    float4 v = *(const float4*)&in[i];
    ushort4 o;
    o.x = __half_as_ushort(__float2half(v.x));
    o.y = __half_as_ushort(__float2half(v.y));
    o.z = __half_as_ushort(__float2half(v.z));
    o.w = __half_as_ushort(__float2half(v.w));
    *(ushort4*)&out[i] = o;
  }
}

// ---- 128x32 f16 staging tile via global_load_lds (16B), XOR swizzle ----
// 256-thread version (2 iters) and 512-thread version (1 iter).
__device__ __forceinline__ void stage_tile(const __half* __restrict__ gbase, int ldg,
                                           _Float16* lds, int t) {
#pragma unroll
  for (int it = 0; it < 2; ++it) {
    const int s  = it * 256 + t;
    const int mp = s >> 3, ps = s & 7;
    const int p  = ps ^ (mp & 7);
    const int r  = mp * 2 + (p >> 2);
    const int q  = p & 3;
    const __half* g = gbase + (size_t)r * ldg + q * 8;
    _Float16* dst = lds + (s >> 6) * 512;
    __builtin_amdgcn_global_load_lds((const __attribute__((address_space(1))) void*)g,
                                     (__attribute__((address_space(3))) void*)dst, 16, 0, 0);
  }
}
// one 128x32 block (8KB), 512 threads, 1x16B load per thread
__device__ __forceinline__ void stage_blk(const __half* __restrict__ gbase, int ldg,
                                          _Float16* lds, int t) {
  const int mp = t >> 3, ps = t & 7;
  const int p  = ps ^ (mp & 7);
  const int r  = mp * 2 + (p >> 2);
  const int q  = p & 3;
  const __half* g = gbase + (size_t)r * ldg + q * 8;
  _Float16* dst = lds + (t >> 6) * 512;
  __builtin_amdgcn_global_load_lds((const __attribute__((address_space(1))) void*)g,
                                   (__attribute__((address_space(3))) void*)dst, 16, 0, 0);
}
__device__ __forceinline__ half8 read_frag(const _Float16* lds, int row, int quad) {
  const int mp = row >> 1;
  const int p  = ((row & 1) << 2) | quad;
  const int ps = p ^ (mp & 7);
  return *(const half8*)(lds + (mp * 8 + ps) * 8);
}

// ---- L64: 64x64 f16 tile, row-major with XOR swizzle on 16B chunks ----
__device__ __forceinline__ void write_l64(_Float16* lds, int row, int col, float v) {
  lds[row * 64 + ((((col >> 3) ^ (row & 7))) << 3) + (col & 7)] = (_Float16)v;
}
__device__ __forceinline__ half8 read_l64c(const _Float16* lds, int row, int c) {
  return *(const half8*)(lds + row * 64 + ((c ^ (row & 7)) << 3));
}

__device__ __forceinline__ void barrier_raw() {
  asm volatile("s_barrier" ::: "memory");
}

// ================= KV HGEMM: 128x256 tile, double-buffered, 2 blk/CU ======
// C = A(32768 x 768) * W(cols [768,2304) x 768)^T + bias, k gets elu+1,
// f16 transposed stores into (B,H,N,64) for k and v.
// 512 threads = 8 waves (2M x 4N), per-wave 64x64 via acc[4][4] -> ~100 regs
// total -> 16 waves/CU (2 blocks). LDS = 2 bufs x 24KB = 48KB.
// Schedule: issue next K-tile's 3 global_load_lds at top, frag reads + 16
// MFMA, vmcnt(0)+barrier at bottom (cover = full iteration; TLP from the
// co-resident block absorbs the residual drain - m114/m97 mechanism).
__global__ __launch_bounds__(512, 4) void hgemm_kv_kernel(
    const __half* __restrict__ A, const __half* __restrict__ W,
    const float* __restrict__ bias,
    __half* __restrict__ outK, __half* __restrict__ outV)
{
  const int K = 768;
  const int NT = 24;                       // 768 / 32
  extern __shared__ __align__(16) _Float16 sh[];   // 2 bufs x 12288 halfs = 48KB
  const int t    = threadIdx.x;
  const int w    = t >> 6;
  const int l    = t & 63;
  const int quad = l >> 4;
  const int mrow = l & 15;
  const int wm   = w >> 2;                 // 0..1 (M, 64-row halves)
  const int wn   = w & 3;                  // 0..3 (N, 64-col quarters)

  // XCD-aware, A-reuse-major: each XCD walks (m-group, j) with j innermost
  // so one 197KB A-panel serves all 6 j-blocks from its L2. 1536 blocks.
  const int bid  = blockIdx.x;
  const int xcd  = bid & 7;
  const int ii   = bid >> 3;               // 0..191
  const int mg   = ii / 6;                 // 0..31
  const int jj   = ii - mg * 6;            // 0..5
  const int m0   = (xcd * 32 + mg) * 128;
  const int j0   = jj * 256;

  floatx4 acc[4][4];
#pragma unroll
  for (int i = 0; i < 4; ++i)
#pragma unroll
    for (int j = 0; j < 4; ++j) acc[i][j] = (floatx4){0.f, 0.f, 0.f, 0.f};

  // prologue: stage K-tile 0 into buf 0 (A 128x32, B 256x32)
  stage_blk(A + (size_t)m0 * K, K, sh, t);
  stage_blk(W + (size_t)(768 + j0) * K, K, sh + 4096, t);
  stage_blk(W + (size_t)(768 + j0 + 128) * K, K, sh + 8192, t);
  asm volatile("s_waitcnt vmcnt(0)" ::: "memory");
  barrier_raw();

#pragma unroll 2
  for (int kt = 0; kt < NT; ++kt) {
    const _Float16* bb = sh + (kt & 1) * 12288;
    _Float16* db = sh + ((kt + 1) & 1) * 12288;
    const bool st = (kt + 1 < NT);
    const int kg = (kt + 1) * 32;

    if (st) {
      stage_blk(A + (size_t)m0 * K + kg, K, db, t);
      stage_blk(W + (size_t)(768 + j0) * K + kg, K, db + 4096, t);
      stage_blk(W + (size_t)(768 + j0 + 128) * K + kg, K, db + 8192, t);
    }

    half8 af[4], bf[4];
#pragma unroll
    for (int j = 0; j < 4; ++j) {
      const int C = wn * 64 + j * 16 + mrow;          // 0..255
      bf[j] = read_frag(bb + 4096 + (C >> 7) * 4096, C & 127, quad);
    }
#pragma unroll
    for (int i = 0; i < 4; ++i)
      af[i] = read_frag(bb, wm * 64 + i * 16 + mrow, quad);
#pragma unroll
    for (int i = 0; i < 4; ++i)
#pragma unroll
      for (int j = 0; j < 4; ++j)
        acc[i][j] = __builtin_amdgcn_mfma_f32_16x16x32_f16(af[i], bf[j], acc[i][j], 0, 0, 0);

    if (st) asm volatile("s_waitcnt vmcnt(0)" ::: "memory");
    barrier_raw();
  }

  // epilogue: per-wave 64x64 of k or v. scr pool = 4 x 8KB (waves share by
  // wm-pass: waves wm==0 first, then wm==1), fits the 48KB buffer space.
  const int col0 = 768 + j0 + wn * 64;         // 64-aligned, in [768,2304)
  const int t3   = col0 / 768;                 // 1=k, 2=v
  const int h    = (col0 - t3 * 768) >> 6;
  __half* dst    = (t3 == 1) ? outK : outV;
  const int m0w  = m0 + wm * 64;
  const int b_   = m0w >> 12;
  const int n0w  = m0w & 4095;
  _Float16* scr  = sh + wn * 4096;             // 8KB per wn
  const size_t gb = ((size_t)(b_ * NHEADS + h) * SEQ + n0w) * 64;

#pragma unroll
  for (int p = 0; p < 2; ++p) {
    if (wm == p) {
#pragma unroll
      for (int j = 0; j < 4; ++j) {
        const int col = j * 16 + mrow;
        const float bsv = bias[col0 + col];
#pragma unroll
        for (int i = 0; i < 4; ++i)
#pragma unroll
          for (int r = 0; r < 4; ++r) {
            const int row = i * 16 + quad * 4 + r;
            float val = acc[i][j][r] + bsv;
            if (t3 == 1) val = (val > 0.f) ? (val + 1.f) : expf(val);  // elu+1
            write_l64(scr, row, col, val);
          }
      }
    }
    barrier_raw();
    if (wm == p) {
#pragma unroll
      for (int it = 0; it < 8; ++it) {
        const int row = it * 8 + (l >> 3);
        const int c   = l & 7;
        half8 vv = read_l64c(scr, row, c);
        *(half8*)((_Float16*)dst + gb + (size_t)row * 64 + c * 8) = vv;
      }
    }
    barrier_raw();
  }
}

// ---------------- HGEMM: C = A(M x 768) * W(rows x 768)^T + bias ------------
// 128x128 tile, 4 waves (2x2), each 64x64 via 4x4 mfma_f32_16x16x32_f16.
// MODE=0 (proj): fp32 row-major outF[m*768+col]. (round-0 proven kernel)
template<int MODE>
__global__ __launch_bounds__(256) void hgemm_kernel(
    const __half* __restrict__ A, const __half* __restrict__ W,
    const float* __restrict__ bias,
    __half* __restrict__ outK, __half* __restrict__ outV,
    float* __restrict__ outF, int colBase)
{
  const int K = 768;
  __shared__ __align__(16) _Float16 sh[16384];  // As|Bs (16KB) U epilogue scratch
  _Float16* As = sh;
  _Float16* Bs = sh + 4096;
  const int t    = threadIdx.x;
  const int w    = t >> 6;
  const int l    = t & 63;
  const int quad = l >> 4;
  const int mrow = l & 15;
  const int m0   = blockIdx.x * 128;
  const int j0   = blockIdx.y * 128;
  const int wr   = (w >> 1) * 64;
  const int wc   = (w & 1) * 64;

  floatx4 acc[4][4];
#pragma unroll
  for (int i = 0; i < 4; ++i)
#pragma unroll
    for (int j = 0; j < 4; ++j) acc[i][j] = (floatx4){0.f, 0.f, 0.f, 0.f};

  for (int k0 = 0; k0 < K; k0 += 32) {
    __syncthreads();
    stage_tile(A + (size_t)m0 * K + k0, K, As, t);
    stage_tile(W + (size_t)(colBase + j0) * K + k0, K, Bs, t);
    __syncthreads();
    half8 af[4], bf[4];
#pragma unroll
    for (int i = 0; i < 4; ++i) af[i] = read_frag(As, wr + i * 16 + mrow, quad);
#pragma unroll
    for (int j = 0; j < 4; ++j) bf[j] = read_frag(Bs, wc + j * 16 + mrow, quad);
#pragma unroll
    for (int i = 0; i < 4; ++i)
#pragma unroll
      for (int j = 0; j < 4; ++j)
        acc[i][j] = __builtin_amdgcn_mfma_f32_16x16x32_f16(af[i], bf[j], acc[i][j], 0, 0, 0);
  }

  if (MODE == 0) {
    // fp32 row-major: 16 lanes x 4B = 64B full-line segments, no RMW
#pragma unroll
    for (int j = 0; j < 4; ++j) {
      const int col = colBase + j0 + wc + j * 16 + mrow;
      const float bsv = bias[col];
#pragma unroll
      for (int i = 0; i < 4; ++i)
#pragma unroll
        for (int r = 0; r < 4; ++r) {
          const int m = m0 + wr + i * 16 + quad * 4 + r;
          outF[(size_t)m * 768 + col] = acc[i][j][r] + bsv;
        }
    }
    return;
  }

  // MODE==1 path unused in this configuration
  const int col0 = colBase + j0 + wc;
  const int t3   = col0 / 768;
  const int h    = (col0 - t3 * 768) >> 6;
  __half* dst    = (t3 == 1) ? outK : outV;
  const int m0w  = m0 + wr;
  const int b_   = m0w >> 12;
  const int n0w  = m0w & 4095;
  _Float16* scr  = sh + w * 4096;

  __syncthreads();
#pragma unroll
  for (int j = 0; j < 4; ++j) {
    const int col = j * 16 + mrow;
    const float bsv = bias[col0 + col];
#pragma unroll
    for (int i = 0; i < 4; ++i)
#pragma unroll
      for (int r = 0; r < 4; ++r) {
        const int row = i * 16 + quad * 4 + r;
        float val = acc[i][j][r] + bsv;
        if (t3 == 1) val = (val > 0.f) ? (val + 1.f) : expf(val);
        write_l64(scr, row, col, val);
      }
  }
  __syncthreads();
  const size_t gb = ((size_t)(b_ * NHEADS + h) * SEQ + n0w) * 64;
#pragma unroll
  for (int it = 0; it < 8; ++it) {
    const int row = it * 8 + (l >> 3);
    const int c   = l & 7;
    half8 vv = read_l64c(scr, row, c);
    *(half8*)((_Float16*)dst + gb + (size_t)row * 64 + c * 8) = vv;
  }
}

// ---------------- kv[b,h,d,e] = sum_n k[n,d]*v[n,e]; ksum[b,h,d] ------------
__global__ __launch_bounds__(256) void kv_kernel(
    const __half* __restrict__ k, const __half* __restrict__ v,
    float* __restrict__ kv, float* __restrict__ ksum)
{
  __shared__ float ks[32 * 64];
  __shared__ float vs[32 * 64];
  const int bh = blockIdx.x;
  const int s  = blockIdx.y;
  const int t  = threadIdx.x;
  const int w  = t >> 6;
  const int l  = t & 63;
  const size_t base = (size_t)bh * SEQ * 64 + (size_t)s * 512 * 64;

  float acc[16];
#pragma unroll
  for (int i = 0; i < 16; ++i) acc[i] = 0.f;
  float kspart = 0.f;

  const int nn0 = t >> 3;
  const int c8  = (t & 7) * 8;

  for (int chunk = 0; chunk < 512; chunk += 32) {
    __syncthreads();
    {
      half8 kk = *(const half8*)&k[base + (size_t)(chunk + nn0) * 64 + c8];
      half8 vv = *(const half8*)&v[base + (size_t)(chunk + nn0) * 64 + c8];
#pragma unroll
      for (int e = 0; e < 8; ++e) {
        ks[nn0 * 64 + c8 + e] = (float)kk[e];
        vs[nn0 * 64 + c8 + e] = (float)vv[e];
      }
    }
    __syncthreads();
#pragma unroll 4
    for (int nn = 0; nn < 32; ++nn) {
      const float ve = vs[nn * 64 + l];
      const float4* kr = (const float4*)&ks[nn * 64 + w * 16];
      float4 k0 = kr[0], k1 = kr[1], k2 = kr[2], k3 = kr[3];
      acc[0]  += k0.x * ve; acc[1]  += k0.y * ve; acc[2]  += k0.z * ve; acc[3]  += k0.w * ve;
      acc[4]  += k1.x * ve; acc[5]  += k1.y * ve; acc[6]  += k1.z * ve; acc[7]  += k1.w * ve;
      acc[8]  += k2.x * ve; acc[9]  += k2.y * ve; acc[10] += k2.z * ve; acc[11] += k2.w * ve;
      acc[12] += k3.x * ve; acc[13] += k3.y * ve; acc[14] += k3.z * ve; acc[15] += k3.w * ve;
      kspart += ks[nn * 64 + l];
    }
  }
#pragma unroll
  for (int i = 0; i < 16; ++i) {
    const int d = w * 16 + i;
    atomicAdd(&kv[((size_t)bh * 64 + d) * 64 + l], acc[i]);
  }
  if (t < 64) atomicAdd(&ksum[(size_t)bh * 64 + l], kspart);
}

// ------- fused Q-GEMM + attention apply -------
__global__ __launch_bounds__(256) void qattn_kernel(
    const __half* __restrict__ A, const __half* __restrict__ W,
    const float* __restrict__ bias,
    const float* __restrict__ kvg, const float* __restrict__ ksumg,
    __half* __restrict__ att)
{
  const int K = 768;
  __shared__ __align__(16) _Float16 sh[24576];  // 48 KB
  _Float16* As = sh;
  _Float16* Bs = sh + 4096;
  __shared__ float norms[256];
  __shared__ float ksums[128];
  const int t    = threadIdx.x;
  const int w    = t >> 6;
  const int l    = t & 63;
  const int quad = l >> 4;
  const int mrow = l & 15;
  const int m0   = blockIdx.x * 128;
  const int j0   = blockIdx.y * 128;
  const int wr   = (w >> 1) * 64;
  const int wc   = (w & 1) * 64;
  const int b_   = m0 >> 12;
  const int h0   = j0 >> 6;

  {
    _Float16* kvT0 = sh + 16384;
#pragma unroll
    for (int ii = 0; ii < 32; ++ii) {
      const int gidx = ii * 256 + t;
      const int head = gidx >> 12;
      const int r    = gidx & 4095;
      const float val = kvg[(size_t)(b_ * NHEADS + h0 + head) * 4096 + r];
      write_l64(kvT0 + head * 4096, r & 63, r >> 6, val);
    }
    if (t < 128) ksums[t] = ksumg[(size_t)(b_ * NHEADS + h0 + (t >> 6)) * 64 + (t & 63)];
  }

  floatx4 acc[4][4];
#pragma unroll
  for (int i = 0; i < 4; ++i)
#pragma unroll
    for (int j = 0; j < 4; ++j) acc[i][j] = (floatx4){0.f, 0.f, 0.f, 0.f};

  for (int k0 = 0; k0 < K; k0 += 32) {
    __syncthreads();
    stage_tile(A + (size_t)m0 * K + k0, K, As, t);
    stage_tile(W + (size_t)j0 * K + k0, K, Bs, t);
    __syncthreads();
    half8 af[4], bf[4];
#pragma unroll
    for (int i = 0; i < 4; ++i) af[i] = read_frag(As, wr + i * 16 + mrow, quad);
#pragma unroll
    for (int j = 0; j < 4; ++j) bf[j] = read_frag(Bs, wc + j * 16 + mrow, quad);
#pragma unroll
    for (int i = 0; i < 4; ++i)
#pragma unroll
      for (int j = 0; j < 4; ++j)
        acc[i][j] = __builtin_amdgcn_mfma_f32_16x16x32_f16(af[i], bf[j], acc[i][j], 0, 0, 0);
  }

  _Float16* qtile = sh + w * 4096;
  const _Float16* kvT = sh + 16384 + (w & 1) * 4096;
  const int hh = w & 1;

  __syncthreads();
#pragma unroll
  for (int j = 0; j < 4; ++j) {
    const int col = j * 16 + mrow;
    const float bsv = bias[j0 + wc + col];
#pragma unroll
    for (int i = 0; i < 4; ++i)
#pragma unroll
      for (int r = 0; r < 4; ++r) {
        const int row = i * 16 + quad * 4 + r;
        float val = acc[i][j][r] + bsv;
        val = (val > 0.f) ? (val + 1.f) : expf(val);
        write_l64(qtile, row, col, val);
      }
  }
  __syncthreads();

  {
    float nrm = 0.f;
#pragma unroll
    for (int c = 0; c < 8; ++c) {
      half8 qv = read_l64c(qtile, l, c);
#pragma unroll
      for (int e = 0; e < 8; ++e) nrm += (float)qv[e] * ksums[hh * 64 + c * 8 + e];
    }
    norms[w * 64 + l] = 1.f / (nrm + 1e-6f);
  }

  floatx4 oacc[4][4];
#pragma unroll
  for (int i = 0; i < 4; ++i)
#pragma unroll
    for (int j = 0; j < 4; ++j) oacc[i][j] = (floatx4){0.f, 0.f, 0.f, 0.f};
#pragma unroll
  for (int ks = 0; ks < 2; ++ks) {
    half8 af[4], bf[4];
#pragma unroll
    for (int i = 0; i < 4; ++i) af[i] = read_l64c(qtile, i * 16 + mrow, ks * 4 + quad);
#pragma unroll
    for (int j = 0; j < 4; ++j) bf[j] = read_l64c(kvT, j * 16 + mrow, ks * 4 + quad);
#pragma unroll
    for (int i = 0; i < 4; ++i)
#pragma unroll
      for (int j = 0; j < 4; ++j)
        oacc[i][j] = __builtin_amdgcn_mfma_f32_16x16x32_f16(af[i], bf[j], oacc[i][j], 0, 0, 0);
  }
  __syncthreads();

#pragma unroll
  for (int i = 0; i < 4; ++i)
#pragma unroll
    for (int r = 0; r < 4; ++r) {
      const int row = i * 16 + quad * 4 + r;
      const float rn = norms[w * 64 + row];
#pragma unroll
      for (int j = 0; j < 4; ++j)
        write_l64(qtile, row, j * 16 + mrow, oacc[i][j][r] * rn);
    }
  __syncthreads();
  const int n0w = (m0 & 4095) + wr;
  const size_t abase = (size_t)(b_ * SEQ + n0w) * 768 + (h0 + hh) * 64;
#pragma unroll
  for (int it = 0; it < 8; ++it) {
    const int row = it * 8 + (l >> 3);
    const int c   = l & 7;
    half8 vv = read_l64c(qtile, row, c);
    *(half8*)((_Float16*)att + abase + (size_t)row * 768 + c * 8) = vv;
  }
}

extern "C" void kernel_launch(void* const* d_in, const int* in_sizes, int n_in,
                              void* d_out, int out_size, void* d_ws, size_t ws_size,
                              hipStream_t stream)
{
  const float* x     = (const float*)d_in[0];
  const float* Wqkv  = (const float*)d_in[1];
  const float* bqkv  = (const float*)d_in[2];
  const float* Wproj = (const float*)d_in[3];
  const float* bproj = (const float*)d_in[4];
  float* out = (float*)d_out;

  const size_t SZ = (size_t)BATCH * NHEADS * SEQ * 64;  // 25,165,824
  __half* xh  = (__half*)d_ws;
  __half* Wqh = xh + SZ;
  __half* Wph = Wqh + (size_t)2304 * 768;
  __half* R3  = Wph + (size_t)768 * 768;   // k -> att
  __half* R4  = R3 + SZ;                   // v
  float*  kvb = (float*)(R4 + SZ);
  float*  ksum = kvb + 96 * 64 * 64;

  zero_kernel<<<1560, 256, 0, stream>>>(kvb, 96 * 64 * 64 + 96 * 64);

  cast_f2h<<<(int)(SZ / 1024), 256, 0, stream>>>(x, xh, (int)SZ);
  cast_f2h<<<(2304 * 768) / 1024, 256, 0, stream>>>(Wqkv, Wqh, 2304 * 768);
  cast_f2h<<<(768 * 768) / 1024, 256, 0, stream>>>(Wproj, Wph, 768 * 768);

  // K,V columns [768, 2304): k -> R3, v -> R4.
  // 1536 blocks (8 XCD x 32 m-groups x 6 j), 2 blocks/CU, 6 rounds.
  hgemm_kv_kernel<<<1536, 512, 49152, stream>>>(xh, Wqh, bqkv, R3, R4);

  kv_kernel<<<dim3(96, 8), 256, 0, stream>>>(R3, R4, kvb, ksum);

  // fused Q-GEMM + attention: att -> R3 (k dead after kv_kernel)
  qattn_kernel<<<dim3(256, 6), 256, 0, stream>>>(
      xh, Wqh, bqkv, kvb, ksum, R3);

  // output projection: fp32 out (round-0 proven 128x128 kernel)
  hgemm_kernel<0><<<dim3(256, 6), 256, 0, stream>>>(
      R3, Wph, bproj, nullptr, nullptr, out, 0);
}

// Round 4
// 440.854 us; speedup vs baseline: 1.1714x; 1.1714x over previous
//
#include <hip/hip_runtime.h>
#include <hip/hip_fp16.h>
#include <math.h>

#define NHEADS 12
#define SEQ 4096
#define BATCH 8

typedef _Float16 half8 __attribute__((ext_vector_type(8)));
typedef float floatx4 __attribute__((ext_vector_type(4)));

// ---------------- zero small accumulators ----------------
__global__ void zero_kernel(float* p, int n) {
  int i = blockIdx.x * 256 + threadIdx.x;
  if (i < n) p[i] = 0.f;
}

// ---------------- fp32 -> fp16 cast, 4 elems/thread ----------------
__global__ void cast_f2h(const float* __restrict__ in, __half* __restrict__ out, int n) {
  int i = (blockIdx.x * 256 + threadIdx.x) * 4;
  if (i < n) {
    float4 v = *(const float4*)&in[i];
    ushort4 o;
    o.x = __half_as_ushort(__float2half(v.x));
    o.y = __half_as_ushort(__float2half(v.y));
    o.z = __half_as_ushort(__float2half(v.z));
    o.w = __half_as_ushort(__float2half(v.w));
    *(ushort4*)&out[i] = o;
  }
}

// ---- 128x32 f16 staging tile via global_load_lds (16B), XOR swizzle ----
// 256-thread version (2 iters) and 512-thread version (1 iter).
__device__ __forceinline__ void stage_tile(const __half* __restrict__ gbase, int ldg,
                                           _Float16* lds, int t) {
#pragma unroll
  for (int it = 0; it < 2; ++it) {
    const int s  = it * 256 + t;
    const int mp = s >> 3, ps = s & 7;
    const int p  = ps ^ (mp & 7);
    const int r  = mp * 2 + (p >> 2);
    const int q  = p & 3;
    const __half* g = gbase + (size_t)r * ldg + q * 8;
    _Float16* dst = lds + (s >> 6) * 512;
    __builtin_amdgcn_global_load_lds((const __attribute__((address_space(1))) void*)g,
                                     (__attribute__((address_space(3))) void*)dst, 16, 0, 0);
  }
}
// one 128x32 block (8KB), 512 threads, 1x16B load per thread
__device__ __forceinline__ void stage_blk(const __half* __restrict__ gbase, int ldg,
                                          _Float16* lds, int t) {
  const int mp = t >> 3, ps = t & 7;
  const int p  = ps ^ (mp & 7);
  const int r  = mp * 2 + (p >> 2);
  const int q  = p & 3;
  const __half* g = gbase + (size_t)r * ldg + q * 8;
  _Float16* dst = lds + (t >> 6) * 512;
  __builtin_amdgcn_global_load_lds((const __attribute__((address_space(1))) void*)g,
                                   (__attribute__((address_space(3))) void*)dst, 16, 0, 0);
}
__device__ __forceinline__ half8 read_frag(const _Float16* lds, int row, int quad) {
  const int mp = row >> 1;
  const int p  = ((row & 1) << 2) | quad;
  const int ps = p ^ (mp & 7);
  return *(const half8*)(lds + (mp * 8 + ps) * 8);
}

// ---- L64: 64x64 f16 tile, row-major with XOR swizzle on 16B chunks ----
__device__ __forceinline__ void write_l64(_Float16* lds, int row, int col, float v) {
  lds[row * 64 + ((((col >> 3) ^ (row & 7))) << 3) + (col & 7)] = (_Float16)v;
}
__device__ __forceinline__ half8 read_l64c(const _Float16* lds, int row, int c) {
  return *(const half8*)(lds + row * 64 + ((c ^ (row & 7)) << 3));
}

__device__ __forceinline__ void barrier_raw() {
  asm volatile("s_barrier" ::: "memory");
}

// ================= 256x256 ring-pipelined HGEMM (R2-proven, 113 us) =======
// C = A(M x 768) * W(rows x 768)^T + bias. 512 threads = 8 waves (2M x 4N),
// per-wave 128x64 via acc[8][4] mfma_f32_16x16x32_f16. BK=32, 4-deep LDS
// ring (4 x 32KB = 128KB dynamic). ONE barrier + ONE counted vmcnt per
// K-tile. A-reuse-major XCD swizzle (j innermost per XCD).
// MODE=1 (KV): cols [768,2304), elu+1 on k; OUTPUT TRANSPOSED: k,v stored
//              as (b,h,d,n) so the downstream kv contraction is n-contiguous.
// MODE=0 (proj): fp32 row-major outF.
template<int MODE>
__global__ __launch_bounds__(512, 2) void hgemm256_kernel(
    const __half* __restrict__ A, const __half* __restrict__ W,
    const float* __restrict__ bias,
    __half* __restrict__ outK, __half* __restrict__ outV,
    float* __restrict__ outF, int colBase)
{
  const int K = 768;
  const int NT = 24;                       // 768 / 32
  extern __shared__ __align__(16) _Float16 sh[];   // 4 bufs x 16384 halfs = 128KB
  const int t    = threadIdx.x;
  const int w    = t >> 6;
  const int l    = t & 63;
  const int quad = l >> 4;
  const int mrow = l & 15;
  const int wm   = w >> 2;                 // 0..1 (M)
  const int wn   = w & 3;                  // 0..3 (N)

  constexpr int JB = (MODE == 1) ? 6 : 3;
  const int bid  = blockIdx.x;
  const int xcd  = bid & 7;
  const int ii   = bid >> 3;               // 0 .. 16*JB-1
  const int mg   = ii / JB;                // 0..15
  const int jj   = ii - mg * JB;           // 0..JB-1
  const int m0   = (xcd * 16 + mg) * 256;
  const int j0   = jj * 256;

  floatx4 acc[8][4];
#pragma unroll
  for (int i = 0; i < 8; ++i)
#pragma unroll
    for (int j = 0; j < 4; ++j) acc[i][j] = (floatx4){0.f, 0.f, 0.f, 0.f};

  // prologue: stage K-tiles 0,1,2 into bufs 0,1,2 (12 loads/thread)
#pragma unroll
  for (int kt = 0; kt < 3; ++kt) {
    _Float16* db = sh + kt * 16384;
    const int kg = kt * 32;
    stage_blk(A + (size_t)m0 * K + kg, K, db, t);
    stage_blk(A + (size_t)(m0 + 128) * K + kg, K, db + 4096, t);
    stage_blk(W + (size_t)(colBase + j0) * K + kg, K, db + 8192, t);
    stage_blk(W + (size_t)(colBase + j0 + 128) * K + kg, K, db + 12288, t);
  }
  asm volatile("s_waitcnt vmcnt(8)" ::: "memory");   // K-tile 0 landed
  barrier_raw();

#pragma unroll 4
  for (int kt = 0; kt < NT; ++kt) {
    const _Float16* bb = sh + (kt & 3) * 16384;
    const bool st = (kt + 3 < NT);
    _Float16* db = sh + ((kt + 3) & 3) * 16384;
    const int kg = (kt + 3) * 32;
    half8 af[4], bf[4];

#pragma unroll
    for (int j = 0; j < 4; ++j) {
      const int C = wn * 64 + j * 16 + mrow;
      bf[j] = read_frag(bb + 8192 + (C >> 7) * 4096, C & 127, quad);
    }
#pragma unroll
    for (int i = 0; i < 4; ++i)
      af[i] = read_frag(bb + wm * 4096, i * 16 + mrow, quad);
    if (st) {
      stage_blk(A + (size_t)m0 * K + kg, K, db, t);
      stage_blk(A + (size_t)(m0 + 128) * K + kg, K, db + 4096, t);
    }
#pragma unroll
    for (int i = 0; i < 4; ++i)
#pragma unroll
      for (int j = 0; j < 4; ++j)
        acc[i][j] = __builtin_amdgcn_mfma_f32_16x16x32_f16(af[i], bf[j], acc[i][j], 0, 0, 0);

#pragma unroll
    for (int i = 0; i < 4; ++i)
      af[i] = read_frag(bb + wm * 4096, (i + 4) * 16 + mrow, quad);
    if (st) {
      stage_blk(W + (size_t)(colBase + j0) * K + kg, K, db + 8192, t);
      stage_blk(W + (size_t)(colBase + j0 + 128) * K + kg, K, db + 12288, t);
    }
#pragma unroll
    for (int i = 0; i < 4; ++i)
#pragma unroll
      for (int j = 0; j < 4; ++j)
        acc[i + 4][j] = __builtin_amdgcn_mfma_f32_16x16x32_f16(af[i], bf[j], acc[i + 4][j], 0, 0, 0);

    if (kt < NT - 3)       asm volatile("s_waitcnt vmcnt(8)" ::: "memory");
    else if (kt == NT - 3) asm volatile("s_waitcnt vmcnt(4)" ::: "memory");
    else if (kt == NT - 2) asm volatile("s_waitcnt vmcnt(0)" ::: "memory");
    barrier_raw();
  }

  if (MODE == 0) {
#pragma unroll
    for (int j = 0; j < 4; ++j) {
      const int col = j0 + wn * 64 + j * 16 + mrow;
      const float bsv = bias[col];
#pragma unroll
      for (int i = 0; i < 8; ++i)
#pragma unroll
        for (int r = 0; r < 4; ++r) {
          const int m = m0 + wm * 128 + i * 16 + quad * 4 + r;
          outF[(size_t)m * 768 + col] = acc[i][j][r] + bsv;
        }
    }
    return;
  }

  // MODE==1: wave tile = 128 rows(n) x one head's 64 cols(d) of k or v.
  // TRANSPOSED emit: scratch tile stored (d, n), global layout (b,h,d,n).
  const int col0 = colBase + j0 + wn * 64;     // 64-aligned, in [768,2304)
  const int t3   = col0 / 768;                 // 1=k, 2=v
  const int h    = (col0 - t3 * 768) >> 6;
  __half* dst    = (t3 == 1) ? outK : outV;
  const int m0w  = m0 + wm * 128;
  const int b_   = m0w >> 12;
  const int n0w  = m0w & 4095;
  _Float16* scr  = sh + w * 4096;              // 8KB per wave (reuse ring LDS)
  const size_t gbT = (size_t)(b_ * NHEADS + h) * 64 * 4096;

#pragma unroll
  for (int hf = 0; hf < 2; ++hf) {
#pragma unroll
    for (int j = 0; j < 4; ++j) {
      const int col = j * 16 + mrow;           // d
      const float bsv = bias[col0 + col];
#pragma unroll
      for (int ii2 = 0; ii2 < 4; ++ii2)
#pragma unroll
        for (int r = 0; r < 4; ++r) {
          const int row = ii2 * 16 + quad * 4 + r;   // n-local
          float val = acc[hf * 4 + ii2][j][r] + bsv;
          if (t3 == 1) val = (val > 0.f) ? (val + 1.f) : expf(val);  // elu+1
          write_l64(scr, col, row, val);             // (d, n) !
        }
    }
    barrier_raw();
#pragma unroll
    for (int it = 0; it < 8; ++it) {
      const int dd = it * 8 + (l >> 3);        // d row
      const int c  = l & 7;                    // n chunk
      half8 vv = read_l64c(scr, dd, c);
      *(half8*)((_Float16*)dst + gbT + (size_t)dd * 4096 + n0w + hf * 64 + c * 8) = vv;
    }
    barrier_raw();
  }
}

// ============ kv via MFMA on transposed k,v: no LDS staging ============
// kT,vT layout (b,h,d,n), n-contiguous. kv[bh][d][e] = sum_n kT[d][n]vT[e][n]
// = A*B^T with K=4096 -> direct-global MFMA fragments (each byte read once,
// no reuse -> staging would be pure overhead). ksum[d] via MFMA against a
// ones-fragment (C[d][*] = row sum). grid (96 bh, 4 n-splits), 4 waves/block
// each owning a 256-n chunk of the full 64x64 output; block LDS-reduce then
// one atomicAdd per element.
__global__ __launch_bounds__(256) void kv_mfma_kernel(
    const __half* __restrict__ kT, const __half* __restrict__ vT,
    float* __restrict__ kv, float* __restrict__ ksum)
{
  extern __shared__ float red[];               // 4*4096 + 4*64 floats = 66.5KB
  float* ksr = red + 4 * 4096;
  const int bh = blockIdx.x;                   // 0..95
  const int sp = blockIdx.y;                   // 0..3
  const int t  = threadIdx.x;
  const int w  = t >> 6;
  const int l  = t & 63;
  const int quad = l >> 4;
  const int mrow = l & 15;
  const size_t base = (size_t)bh * 64 * 4096;
  const int n0 = sp * 1024 + w * 256;

  floatx4 acc[4][4];
  floatx4 ks[4];
#pragma unroll
  for (int i = 0; i < 4; ++i) {
    ks[i] = (floatx4){0.f, 0.f, 0.f, 0.f};
#pragma unroll
    for (int j = 0; j < 4; ++j) acc[i][j] = (floatx4){0.f, 0.f, 0.f, 0.f};
  }
  half8 ones;
#pragma unroll
  for (int e = 0; e < 8; ++e) ones[e] = (_Float16)1.0f;

  // per-lane row base pointers (rows i*16+mrow of kT / vT)
  const __half* pk[4];
  const __half* pv[4];
#pragma unroll
  for (int i = 0; i < 4; ++i) {
    pk[i] = kT + base + (size_t)(i * 16 + mrow) * 4096 + n0 + quad * 8;
    pv[i] = vT + base + (size_t)(i * 16 + mrow) * 4096 + n0 + quad * 8;
  }

#pragma unroll
  for (int nn = 0; nn < 256; nn += 32) {
    half8 af[4], bf[4];
#pragma unroll
    for (int i = 0; i < 4; ++i) af[i] = *(const half8*)(pk[i] + nn);
#pragma unroll
    for (int j = 0; j < 4; ++j) bf[j] = *(const half8*)(pv[j] + nn);
#pragma unroll
    for (int i = 0; i < 4; ++i)
#pragma unroll
      for (int j = 0; j < 4; ++j)
        acc[i][j] = __builtin_amdgcn_mfma_f32_16x16x32_f16(af[i], bf[j], acc[i][j], 0, 0, 0);
#pragma unroll
    for (int i = 0; i < 4; ++i)
      ks[i] = __builtin_amdgcn_mfma_f32_16x16x32_f16(af[i], ones, ks[i], 0, 0, 0);
  }

  // block reduce: wave w writes its 64x64 tile, then 4-way sum + atomic
  float* rw = red + w * 4096;
#pragma unroll
  for (int i = 0; i < 4; ++i)
#pragma unroll
    for (int j = 0; j < 4; ++j)
#pragma unroll
      for (int r = 0; r < 4; ++r)
        rw[(i * 16 + quad * 4 + r) * 64 + j * 16 + mrow] = acc[i][j][r];
  if (mrow == 0) {
#pragma unroll
    for (int i = 0; i < 4; ++i)
#pragma unroll
      for (int r = 0; r < 4; ++r)
        ksr[w * 64 + i * 16 + quad * 4 + r] = ks[i][r];
  }
  __syncthreads();
#pragma unroll
  for (int ii = 0; ii < 16; ++ii) {
    const int idx = ii * 256 + t;
    const float s = red[idx] + red[4096 + idx] + red[8192 + idx] + red[12288 + idx];
    atomicAdd(&kv[(size_t)bh * 4096 + idx], s);
  }
  if (t < 64)
    atomicAdd(&ksum[(size_t)bh * 64 + t], ksr[t] + ksr[64 + t] + ksr[128 + t] + ksr[192 + t]);
}

// ------- fused Q-GEMM + attention apply -------
__global__ __launch_bounds__(256) void qattn_kernel(
    const __half* __restrict__ A, const __half* __restrict__ W,
    const float* __restrict__ bias,
    const float* __restrict__ kvg, const float* __restrict__ ksumg,
    __half* __restrict__ att)
{
  const int K = 768;
  __shared__ __align__(16) _Float16 sh[24576];  // 48 KB
  _Float16* As = sh;
  _Float16* Bs = sh + 4096;
  __shared__ float norms[256];
  __shared__ float ksums[128];
  const int t    = threadIdx.x;
  const int w    = t >> 6;
  const int l    = t & 63;
  const int quad = l >> 4;
  const int mrow = l & 15;
  const int m0   = blockIdx.x * 128;
  const int j0   = blockIdx.y * 128;
  const int wr   = (w >> 1) * 64;
  const int wc   = (w & 1) * 64;
  const int b_   = m0 >> 12;
  const int h0   = j0 >> 6;

  {
    _Float16* kvT0 = sh + 16384;
#pragma unroll
    for (int ii = 0; ii < 32; ++ii) {
      const int gidx = ii * 256 + t;
      const int head = gidx >> 12;
      const int r    = gidx & 4095;
      const float val = kvg[(size_t)(b_ * NHEADS + h0 + head) * 4096 + r];
      write_l64(kvT0 + head * 4096, r & 63, r >> 6, val);
    }
    if (t < 128) ksums[t] = ksumg[(size_t)(b_ * NHEADS + h0 + (t >> 6)) * 64 + (t & 63)];
  }

  floatx4 acc[4][4];
#pragma unroll
  for (int i = 0; i < 4; ++i)
#pragma unroll
    for (int j = 0; j < 4; ++j) acc[i][j] = (floatx4){0.f, 0.f, 0.f, 0.f};

  for (int k0 = 0; k0 < K; k0 += 32) {
    __syncthreads();
    stage_tile(A + (size_t)m0 * K + k0, K, As, t);
    stage_tile(W + (size_t)j0 * K + k0, K, Bs, t);
    __syncthreads();
    half8 af[4], bf[4];
#pragma unroll
    for (int i = 0; i < 4; ++i) af[i] = read_frag(As, wr + i * 16 + mrow, quad);
#pragma unroll
    for (int j = 0; j < 4; ++j) bf[j] = read_frag(Bs, wc + j * 16 + mrow, quad);
#pragma unroll
    for (int i = 0; i < 4; ++i)
#pragma unroll
      for (int j = 0; j < 4; ++j)
        acc[i][j] = __builtin_amdgcn_mfma_f32_16x16x32_f16(af[i], bf[j], acc[i][j], 0, 0, 0);
  }

  _Float16* qtile = sh + w * 4096;
  const _Float16* kvT = sh + 16384 + (w & 1) * 4096;
  const int hh = w & 1;

  __syncthreads();
#pragma unroll
  for (int j = 0; j < 4; ++j) {
    const int col = j * 16 + mrow;
    const float bsv = bias[j0 + wc + col];
#pragma unroll
    for (int i = 0; i < 4; ++i)
#pragma unroll
      for (int r = 0; r < 4; ++r) {
        const int row = i * 16 + quad * 4 + r;
        float val = acc[i][j][r] + bsv;
        val = (val > 0.f) ? (val + 1.f) : expf(val);
        write_l64(qtile, row, col, val);
      }
  }
  __syncthreads();

  {
    float nrm = 0.f;
#pragma unroll
    for (int c = 0; c < 8; ++c) {
      half8 qv = read_l64c(qtile, l, c);
#pragma unroll
      for (int e = 0; e < 8; ++e) nrm += (float)qv[e] * ksums[hh * 64 + c * 8 + e];
    }
    norms[w * 64 + l] = 1.f / (nrm + 1e-6f);
  }

  floatx4 oacc[4][4];
#pragma unroll
  for (int i = 0; i < 4; ++i)
#pragma unroll
    for (int j = 0; j < 4; ++j) oacc[i][j] = (floatx4){0.f, 0.f, 0.f, 0.f};
#pragma unroll
  for (int ks = 0; ks < 2; ++ks) {
    half8 af[4], bf[4];
#pragma unroll
    for (int i = 0; i < 4; ++i) af[i] = read_l64c(qtile, i * 16 + mrow, ks * 4 + quad);
#pragma unroll
    for (int j = 0; j < 4; ++j) bf[j] = read_l64c(kvT, j * 16 + mrow, ks * 4 + quad);
#pragma unroll
    for (int i = 0; i < 4; ++i)
#pragma unroll
      for (int j = 0; j < 4; ++j)
        oacc[i][j] = __builtin_amdgcn_mfma_f32_16x16x32_f16(af[i], bf[j], oacc[i][j], 0, 0, 0);
  }
  __syncthreads();

#pragma unroll
  for (int i = 0; i < 4; ++i)
#pragma unroll
    for (int r = 0; r < 4; ++r) {
      const int row = i * 16 + quad * 4 + r;
      const float rn = norms[w * 64 + row];
#pragma unroll
      for (int j = 0; j < 4; ++j)
        write_l64(qtile, row, j * 16 + mrow, oacc[i][j][r] * rn);
    }
  __syncthreads();
  const int n0w = (m0 & 4095) + wr;
  const size_t abase = (size_t)(b_ * SEQ + n0w) * 768 + (h0 + hh) * 64;
#pragma unroll
  for (int it = 0; it < 8; ++it) {
    const int row = it * 8 + (l >> 3);
    const int c   = l & 7;
    half8 vv = read_l64c(qtile, row, c);
    *(half8*)((_Float16*)att + abase + (size_t)row * 768 + c * 8) = vv;
  }
}

extern "C" void kernel_launch(void* const* d_in, const int* in_sizes, int n_in,
                              void* d_out, int out_size, void* d_ws, size_t ws_size,
                              hipStream_t stream)
{
  const float* x     = (const float*)d_in[0];
  const float* Wqkv  = (const float*)d_in[1];
  const float* bqkv  = (const float*)d_in[2];
  const float* Wproj = (const float*)d_in[3];
  const float* bproj = (const float*)d_in[4];
  float* out = (float*)d_out;

  const size_t SZ = (size_t)BATCH * NHEADS * SEQ * 64;  // 25,165,824
  __half* xh  = (__half*)d_ws;
  __half* Wqh = xh + SZ;
  __half* Wph = Wqh + (size_t)2304 * 768;
  __half* R3  = Wph + (size_t)768 * 768;   // kT -> att
  __half* R4  = R3 + SZ;                   // vT
  float*  kvb = (float*)(R4 + SZ);
  float*  ksum = kvb + 96 * 64 * 64;

  static bool attr_set = false;
  if (!attr_set) {
    hipFuncSetAttribute((const void*)hgemm256_kernel<1>,
                        hipFuncAttributeMaxDynamicSharedMemorySize, 131072);
    hipFuncSetAttribute((const void*)hgemm256_kernel<0>,
                        hipFuncAttributeMaxDynamicSharedMemorySize, 131072);
    hipFuncSetAttribute((const void*)kv_mfma_kernel,
                        hipFuncAttributeMaxDynamicSharedMemorySize, 66560);
    attr_set = true;
  }

  zero_kernel<<<1560, 256, 0, stream>>>(kvb, 96 * 64 * 64 + 96 * 64);

  cast_f2h<<<(int)(SZ / 1024), 256, 0, stream>>>(x, xh, (int)SZ);
  cast_f2h<<<(2304 * 768) / 1024, 256, 0, stream>>>(Wqkv, Wqh, 2304 * 768);
  cast_f2h<<<(768 * 768) / 1024, 256, 0, stream>>>(Wproj, Wph, 768 * 768);

  // K,V columns [768, 2304): kT -> R3, vT -> R4, layout (b,h,d,n).
  hgemm256_kernel<1><<<768, 512, 131072, stream>>>(
      xh, Wqh, bqkv, R3, R4, nullptr, 768);

  // kv + ksum via MFMA on the transposed layout
  kv_mfma_kernel<<<dim3(96, 4), 256, 66560, stream>>>(R3, R4, kvb, ksum);

  // fused Q-GEMM + attention: att -> R3 (kT dead after kv_mfma_kernel)
  qattn_kernel<<<dim3(256, 6), 256, 0, stream>>>(
      xh, Wqh, bqkv, kvb, ksum, R3);

  // output projection: fp32 out
  hgemm256_kernel<0><<<384, 512, 131072, stream>>>(
      R3, Wph, bproj, nullptr, nullptr, out, 0);
}